// Round 1
// baseline (764.079 us; speedup 1.0000x reference)
//
#include <hip/hip_runtime.h>
#include <math.h>

#define F_IN 256
#define CH   16
#define NL   7

// ---------------------------------------------------------------- degree (counting-sort histogram)
__global__ void k_degree(const int* __restrict__ dst, int E, int* __restrict__ deg) {
    int i = blockIdx.x * blockDim.x + threadIdx.x;
    if (i < E) atomicAdd(&deg[dst[i]], 1);
}

// ---------------------------------------------------------------- scan A: per-block exclusive scan + block totals
__global__ __launch_bounds__(256) void k_scanA(const int* __restrict__ deg, int N,
                                               int* __restrict__ excl, int* __restrict__ partial) {
    __shared__ int sm[256];
    int tid = threadIdx.x;
    int i = blockIdx.x * 256 + tid;
    int v = (i < N) ? deg[i] : 0;
    sm[tid] = v;
    __syncthreads();
    for (int off = 1; off < 256; off <<= 1) {
        int t = (tid >= off) ? sm[tid - off] : 0;
        __syncthreads();
        sm[tid] += t;
        __syncthreads();
    }
    if (i < N) excl[i] = sm[tid] - v;
    if (tid == 255) partial[blockIdx.x] = sm[255];
}

// ---------------------------------------------------------------- scan B: exclusive scan of block totals (1 block; NB<=1024)
__global__ __launch_bounds__(1024) void k_scanB(int* __restrict__ partial, int nb) {
    __shared__ int sm[1024];
    int tid = threadIdx.x;
    int v = (tid < nb) ? partial[tid] : 0;
    sm[tid] = v;
    __syncthreads();
    for (int off = 1; off < 1024; off <<= 1) {
        int t = (tid >= off) ? sm[tid - off] : 0;
        __syncthreads();
        sm[tid] += t;
        __syncthreads();
    }
    if (tid < nb) partial[tid] = sm[tid] - v;
}

// ---------------------------------------------------------------- scan C: add block offsets, init cursor, rowptr[N]=E
__global__ __launch_bounds__(256) void k_scanC(int* __restrict__ rowptr, const int* __restrict__ partial,
                                               int* __restrict__ cursor, int N, int E) {
    int i = blockIdx.x * 256 + threadIdx.x;
    if (i < N) {
        int r = rowptr[i] + partial[blockIdx.x];
        rowptr[i] = r;
        cursor[i] = r;
    }
    if (i == 0) rowptr[N] = E;
}

// ---------------------------------------------------------------- counting-sort scatter: src grouped by dst
__global__ void k_scatter(const int* __restrict__ src, const int* __restrict__ dst, int E,
                          int* __restrict__ cursor, int* __restrict__ sorted_src) {
    int i = blockIdx.x * blockDim.x + threadIdx.x;
    if (i >= E) return;
    int slot = atomicAdd(&cursor[dst[i]], 1);
    sorted_src[slot] = src[i];
}

// ---------------------------------------------------------------- gemm1: g = (x @ W0) * dinv
// one wave per row; lane = q*16 + c  (q = k-quarter, c = out channel)
__global__ __launch_bounds__(256) void k_gemm1(const float* __restrict__ x,
                                               const float* __restrict__ W0,
                                               const int* __restrict__ deg,
                                               float* __restrict__ g, int N) {
    int lane = threadIdx.x & 63;
    int q = lane >> 4;   // which quarter of K (64 k's each)
    int c = lane & 15;   // output channel
    float w[64];
#pragma unroll
    for (int t = 0; t < 64; ++t) w[t] = W0[(q * 64 + t) * CH + c];

    int wave  = (blockIdx.x * blockDim.x + threadIdx.x) >> 6;
    int nwave = (gridDim.x * blockDim.x) >> 6;
    for (int row = wave; row < N; row += nwave) {
        const float4* xp = (const float4*)(x + row * F_IN + q * 64);
        float acc = 0.f;
#pragma unroll
        for (int t = 0; t < 16; ++t) {
            float4 v = xp[t];
            acc += v.x * w[4*t] + v.y * w[4*t+1] + v.z * w[4*t+2] + v.w * w[4*t+3];
        }
        acc += __shfl_xor(acc, 16);
        acc += __shfl_xor(acc, 32);
        if (q == 0) {
            float dinv = rsqrtf((float)(deg[row] + 1));
            g[row * CH + c] = acc * dinv;
        }
    }
}

// ---------------------------------------------------------------- agg1: pull-gather layer1 + fused relu + W1 + dinv
// 16 lanes per node (c = channel); per edge read one 64B row of g
__global__ __launch_bounds__(256) void k_agg1(const float* __restrict__ g,
                                              const int* __restrict__ rowptr,
                                              const int* __restrict__ sorted_src,
                                              const float* __restrict__ W1,
                                              const int* __restrict__ deg,
                                              float* __restrict__ g2, int N) {
    int c = threadIdx.x & 15;
    float w1[NL];
#pragma unroll
    for (int j = 0; j < NL; ++j) w1[j] = W1[c * NL + j];

    int grp  = (blockIdx.x * blockDim.x + threadIdx.x) >> 4;
    int ngrp = (gridDim.x * blockDim.x) >> 4;
    for (int d = grp; d < N; d += ngrp) {
        int beg = rowptr[d], end = rowptr[d + 1];
        float acc = g[d * CH + c];              // self-loop term (already *dinv_d)
        int e = beg;
        for (; e + 4 <= end; e += 4) {          // 4 outstanding gathers for MLP
            int s0 = sorted_src[e],   s1 = sorted_src[e+1];
            int s2 = sorted_src[e+2], s3 = sorted_src[e+3];
            float a0 = g[s0*CH+c], a1 = g[s1*CH+c];
            float a2 = g[s2*CH+c], a3 = g[s3*CH+c];
            acc += (a0 + a1) + (a2 + a3);
        }
        for (; e < end; ++e) acc += g[sorted_src[e]*CH + c];

        float dinv = rsqrtf((float)(deg[d] + 1));
        float h = fmaxf(acc * dinv, 0.f);       // h2[d][c]
        float y = 0.f;
#pragma unroll
        for (int j = 0; j < NL; ++j) {          // y_j = sum_c h_c * W1[c][j]
            float p = h * w1[j];
            p += __shfl_xor(p, 8, 16);
            p += __shfl_xor(p, 4, 16);
            p += __shfl_xor(p, 2, 16);
            p += __shfl_xor(p, 1, 16);
            if (c == j) y = p;
        }
        if (c < 8) g2[d * 8 + c] = (c < NL) ? y * dinv : 0.f;
    }
}

// ---------------------------------------------------------------- agg2: pull-gather layer2 + fused exp epilogue
// 8 lanes per node (j = output channel, padded to 8)
__global__ __launch_bounds__(256) void k_agg2(const float* __restrict__ g2,
                                              const int* __restrict__ rowptr,
                                              const int* __restrict__ sorted_src,
                                              const int* __restrict__ deg,
                                              float* __restrict__ out, int N) {
    int j = threadIdx.x & 7;
    int grp  = (blockIdx.x * blockDim.x + threadIdx.x) >> 3;
    int ngrp = (gridDim.x * blockDim.x) >> 3;
    for (int d = grp; d < N; d += ngrp) {
        int beg = rowptr[d], end = rowptr[d + 1];
        float acc = g2[d * 8 + j];              // self-loop term
        int e = beg;
        for (; e + 4 <= end; e += 4) {
            int s0 = sorted_src[e],   s1 = sorted_src[e+1];
            int s2 = sorted_src[e+2], s3 = sorted_src[e+3];
            acc += (g2[s0*8+j] + g2[s1*8+j]) + (g2[s2*8+j] + g2[s3*8+j]);
        }
        for (; e < end; ++e) acc += g2[sorted_src[e]*8 + j];
        if (j < NL) {
            float dinv = rsqrtf((float)(deg[d] + 1));
            out[d * NL + j] = __expf(dinv * acc) + 1.0f;
        }
    }
}

extern "C" void kernel_launch(void* const* d_in, const int* in_sizes, int n_in,
                              void* d_out, int out_size, void* d_ws, size_t ws_size,
                              hipStream_t stream) {
    const float* x  = (const float*)d_in[0];
    const float* W0 = (const float*)d_in[1];
    const float* W1 = (const float*)d_in[2];
    const int*   ei = (const int*)d_in[3];

    const int N = in_sizes[0] / F_IN;       // 100000
    const int E = in_sizes[3] / 2;          // 3200000
    const int* src = ei;
    const int* dst = ei + E;
    const int NB = (N + 255) / 256;         // 391 <= 1024 (k_scanB limit)

    // workspace layout (ints/floats, ~24 MB):
    // deg[N] | rowptr[N+1] | cursor[N] | partial[1024] | sorted_src[E] | g[N*16] | g2[N*8]
    int* deg     = (int*)d_ws;
    int* rowptr  = deg + N;
    int* cursor  = rowptr + (N + 1);
    int* partial = cursor + N;
    int* sorted  = partial + 1024;
    float* g     = (float*)(sorted + E);
    float* g2    = g + (size_t)N * CH;

    float* out = (float*)d_out;

    // only the histogram needs zeroing now (no dense accumulators)
    hipMemsetAsync(deg, 0, (size_t)N * sizeof(int), stream);

    // 1) degree histogram
    k_degree<<<(E + 255) / 256, 256, 0, stream>>>(dst, E, deg);

    // 2) rowptr = exclusive_scan(deg); cursor = rowptr
    k_scanA<<<NB, 256, 0, stream>>>(deg, N, rowptr, partial);
    k_scanB<<<1, 1024, 0, stream>>>(partial, NB);
    k_scanC<<<NB, 256, 0, stream>>>(rowptr, partial, cursor, N, E);

    // 3) counting-sort scatter: sorted_src grouped by dst (E int atomics)
    k_scatter<<<(E + 255) / 256, 256, 0, stream>>>(src, dst, E, cursor, sorted);

    // 4) g = (x@W0) * dinv   (memory-bound on x: 102 MB)
    k_gemm1<<<2048, 256, 0, stream>>>(x, W0, deg, g, N);

    // 5) layer1 pull-aggregate + relu + W1 + dinv  -> g2 (replaces k_edge1/k_layer2)
    k_agg1<<<2048, 256, 0, stream>>>(g, rowptr, sorted, W1, deg, g2, N);

    // 6) layer2 pull-aggregate + exp epilogue      -> out (replaces k_edge2/k_final)
    k_agg2<<<2048, 256, 0, stream>>>(g2, rowptr, sorted, deg, out, N);
}